// Round 20
// baseline (1513.021 us; speedup 1.0000x reference)
//
#include <hip/hip_runtime.h>
#include <hip/hip_bf16.h>

// ============================================================================
// ROUND 20 = COUNTER PROBES on the CURRENT gemm body (burst-stage + coalesced
// B + tile directory). Three >=380us dispatches enter rocprof top-5:
//   probe_full (body x16), probe_stage (stage x64), probe_comp (compute x64).
// Real pipeline runs last, unchanged -> validated output. dur sacrificial.
// ============================================================================

#define BATCH   8192
#define NGRP    8
#define MAXGS   64
#define DMODEL  2048
#define TM      16
#define NBLK    32
#define NKK     (DMODEL / 32)
#define MAXTILES 520

typedef __attribute__((ext_vector_type(8))) short  short8;
typedef __attribute__((ext_vector_type(4))) float  f32x4;
typedef __attribute__((ext_vector_type(4))) short  short4v;

#define CNT_OFF   0
#define HIST_OFF  512
#define MAP_OFF   1536
#define LISTS_OFF 4096
#define W_OFF     (LISTS_OFF + NGRP * BATCH * 4)
#define CNT_STRIDE 16

static __device__ __forceinline__ short bf(float f) {
    __hip_bfloat16 h = __float2bfloat16(f);
    return (short)__bfloat16_as_ushort(h);
}

__global__ __launch_bounds__(256) void init_hist_kernel(
    const float* __restrict__ W,
    const int* __restrict__ chosen,
    unsigned short* __restrict__ Wb2,
    int* __restrict__ hist)
{
    int blk = blockIdx.x;
    int tid = threadIdx.x;
    if (blk < 1024) {
        int e = (blk * 256 + tid) * 4;
        int g = e >> 17;
        int rem = e & ((MAXGS * DMODEL) - 1);
        int c = rem >> 11;
        int k = rem & (DMODEL - 1);
        int kk = k >> 5, j = k & 31;
        float4 w = *reinterpret_cast<const float4*>(W + e);
        ushort4 o;
        o.x = (unsigned short)bf(w.x); o.y = (unsigned short)bf(w.y);
        o.z = (unsigned short)bf(w.z); o.w = (unsigned short)bf(w.w);
        size_t dst = (((size_t)g * NKK + kk) * MAXGS + c) * 32 + j;
        *reinterpret_cast<ushort4*>(Wb2 + dst) = o;
    } else {
        int hb = blk - 1024;
        __shared__ int h[NGRP];
        if (tid < NGRP) h[tid] = 0;
        __syncthreads();
        int g = chosen[hb * 256 + tid];
        atomicAdd(&h[g], 1);
        __syncthreads();
        if (tid < NGRP) hist[hb * NGRP + tid] = h[tid];
    }
}

__global__ __launch_bounds__(256) void scatter_kernel(const int* __restrict__ chosen,
                                                      const int* __restrict__ hist,
                                                      int* __restrict__ lists,
                                                      int* __restrict__ cnt,
                                                      int* __restrict__ map) {
    __shared__ int hloc[NBLK * NGRP];
    __shared__ int gbase[NGRP];
    __shared__ int ntl[NGRP];
    __shared__ int wcnt[4][NGRP];
    __shared__ int wbase[4][NGRP];
    int tid  = threadIdx.x;
    int blk  = blockIdx.x;
    int w    = tid >> 6;
    int lane = tid & 63;

    if (tid < NBLK * NGRP) hloc[tid] = hist[tid];
    __syncthreads();
    if (tid < NGRP) {
        int s = 0;
        for (int b2 = 0; b2 < blk; ++b2) s += hloc[b2 * NGRP + tid];
        gbase[tid] = s;
        int tot = s;
        for (int b2 = blk; b2 < NBLK; ++b2) tot += hloc[b2 * NGRP + tid];
        ntl[tid] = (tot + TM - 1) / TM;
        if (blk == 0) cnt[tid * CNT_STRIDE] = tot;
    }
    __syncthreads();

    if (blk == 0) {
        for (int q = tid; q < MAXTILES; q += 256) map[q] = -1;
        __syncthreads();
        for (int p = tid; p < NGRP * 512; p += 256) {
            int t = p >> 3, gg = p & 7;
            if (t < ntl[gg]) {
                int pos = 0;
                #pragma unroll
                for (int g2 = 0; g2 < NGRP; ++g2) {
                    int nt = ntl[g2];
                    pos += (t < nt ? t : nt);
                    pos += (g2 < gg && nt > t) ? 1 : 0;
                }
                map[pos] = (gg << 16) | t;
            }
        }
    }

    int b = blk * 256 + tid;
    int g = chosen[b];
    int rank = 0;
    unsigned long long below = (1ull << lane) - 1ull;
    #pragma unroll
    for (int gg = 0; gg < NGRP; ++gg) {
        unsigned long long m = __ballot(g == gg);
        if (g == gg) rank = __popcll(m & below);
        if (lane == gg) wcnt[w][gg] = __popcll(m);
    }
    __syncthreads();
    if (tid < NGRP) {
        int base = gbase[tid];
        #pragma unroll
        for (int ww = 0; ww < 4; ++ww) {
            wbase[ww][tid] = base;
            base += wcnt[ww][tid];
        }
    }
    __syncthreads();
    lists[g * BATCH + wbase[w][g] + rank] = b;
}

// ---------- shared pieces of the gemm body (macro-free, inlined) ----------
// STAGE body: wave w stages rows 4w..4w+3, 8KB burst each, swizzled ds_write.
// dep: asm-opaque 0 added to source offsets (defeats cross-rep CSE).
static __device__ __forceinline__ void stage_body(
    const float* const src[4], unsigned short (*A)[DMODEL],
    int w, int lane, int dep)
{
    f32x4 ra[8], rb[8];
    #pragma unroll
    for (int h = 0; h < 8; ++h)
        ra[h] = *reinterpret_cast<const f32x4*>(src[0] + dep + h * 256);
    #pragma unroll
    for (int h = 0; h < 8; ++h)
        rb[h] = *reinterpret_cast<const f32x4*>(src[1] + dep + h * 256);
    #pragma unroll
    for (int i = 0; i < 4; ++i) {
        int r = 4 * w + i;
        int swz = ((r & 7) << 4) | ((r & 1) << 6);
        char* abase = (char*)&A[r][0];
        #pragma unroll
        for (int h = 0; h < 8; ++h) {
            f32x4 v = ra[h];
            short4v o;
            o[0] = bf(v[0]); o[1] = bf(v[1]); o[2] = bf(v[2]); o[3] = bf(v[3]);
            int byte = (h * 512 + lane * 8) ^ swz;
            *reinterpret_cast<short4v*>(abase + byte) = o;
        }
        if (i < 3) {
            #pragma unroll
            for (int h = 0; h < 8; ++h) ra[h] = rb[h];
            if (i < 2) {
                #pragma unroll
                for (int h = 0; h < 8; ++h)
                    rb[h] = *reinterpret_cast<const f32x4*>(src[i + 2] + dep + h * 256);
            }
        }
    }
}

static __device__ __forceinline__ void compute_body(
    const unsigned short (*A)[DMODEL], const unsigned short* bp,
    const float* bias, const int* gsizes, const int* lists, float* out,
    int g, int m0, int c, int w, int lrow, int kg, int dep)
{
    int swzr = ((lrow & 7) << 4) | ((lrow & 1) << 6);
    const char* arow = (const char*)&A[lrow][0];
    f32x4 acc = f32x4{0, 0, 0, 0};
    #pragma unroll 8
    for (int kk = 0; kk < NKK; ++kk) {
        int byte = (kk * 64 + kg * 16) ^ swzr;
        short8 af  = *reinterpret_cast<const short8*>(arow + byte);
        short8 bfr = *reinterpret_cast<const short8*>(bp + dep + (size_t)kk * MAXGS * 32);
        acc = __builtin_amdgcn_mfma_f32_16x16x32_bf16(af, bfr, acc, 0, 0, 0);
    }
    int gsz = gsizes[g];
    int n = w * 16 + lrow;
    float bv = bias[g * MAXGS + n];
    #pragma unroll
    for (int r = 0; r < 4; ++r) {
        int m = m0 + kg * 4 + r;
        if (m < c) {
            int s = lists[g * BATCH + m];
            out[(size_t)s * MAXGS + n] = acc[r] + bv;
            out[(size_t)(BATCH + s) * MAXGS + n] = (n < gsz) ? 1.0f : 0.0f;
        }
    }
}

// ---------------- REAL gemm (r19 body, unchanged semantics) ----------------
__global__ __launch_bounds__(256, 2) void gemm_kernel(
    const float* __restrict__ hidden, const float* __restrict__ bias,
    const int* __restrict__ gsizes, const int* __restrict__ cnt,
    const int* __restrict__ lists, const int* __restrict__ map,
    const unsigned short* __restrict__ Wb2, float* __restrict__ out)
{
    int e = map[blockIdx.x];
    if (e < 0) return;
    int g = e >> 16, t = e & 0xFFFF;
    int c = cnt[g * CNT_STRIDE];
    int m0 = t * TM;
    __shared__ unsigned short A[TM][DMODEL];
    int tid = threadIdx.x, w = tid >> 6, lane = tid & 63;
    int lrow = lane & 15, kg = lane >> 4;

    const float* src[4];
    #pragma unroll
    for (int i = 0; i < 4; ++i) {
        int m = m0 + 4 * w + i;
        int ms = m < c ? m : c - 1;
        src[i] = hidden + ((size_t)lists[g * BATCH + ms] * NGRP + g) * DMODEL + lane * 4;
    }
    stage_body(src, A, w, lane, 0);
    __syncthreads();
    const unsigned short* bp =
        Wb2 + (size_t)g * NKK * MAXGS * 32 + (w * 16 + lrow) * 32 + kg * 8;
    compute_body(A, bp, bias, gsizes, lists, out, g, m0, c, w, lrow, kg, 0);
}

// ---------------- PROBE: full body x16 ----------------
__global__ __launch_bounds__(256, 2) void probe_full(
    const float* __restrict__ hidden, const float* __restrict__ bias,
    const int* __restrict__ gsizes, const int* __restrict__ cnt,
    const int* __restrict__ lists, const int* __restrict__ map,
    const unsigned short* __restrict__ Wb2, float* __restrict__ out)
{
    int e = map[blockIdx.x];
    if (e < 0) return;
    int g = e >> 16, t = e & 0xFFFF;
    int c = cnt[g * CNT_STRIDE];
    int m0 = t * TM;
    __shared__ unsigned short A[TM][DMODEL];
    int tid = threadIdx.x, w = tid >> 6, lane = tid & 63;
    int lrow = lane & 15, kg = lane >> 4;
    const float* src[4];
    #pragma unroll
    for (int i = 0; i < 4; ++i) {
        int m = m0 + 4 * w + i;
        int ms = m < c ? m : c - 1;
        src[i] = hidden + ((size_t)lists[g * BATCH + ms] * NGRP + g) * DMODEL + lane * 4;
    }
    const unsigned short* bp =
        Wb2 + (size_t)g * NKK * MAXGS * 32 + (w * 16 + lrow) * 32 + kg * 8;
    int dep = 0;
    for (int rep = 0; rep < 16; ++rep) {
        asm volatile("" : "+v"(dep));
        stage_body(src, A, w, lane, dep);
        __syncthreads();
        compute_body(A, bp, bias, gsizes, lists, out, g, m0, c, w, lrow, kg, dep);
        __syncthreads();
    }
}

// ---------------- PROBE: stage-only x64 ----------------
__global__ __launch_bounds__(256, 2) void probe_stage(
    const float* __restrict__ hidden,
    const int* __restrict__ cnt, const int* __restrict__ lists,
    const int* __restrict__ map)
{
    int e = map[blockIdx.x];
    if (e < 0) return;
    int g = e >> 16, t = e & 0xFFFF;
    int c = cnt[g * CNT_STRIDE];
    int m0 = t * TM;
    __shared__ unsigned short A[TM][DMODEL];
    int tid = threadIdx.x, w = tid >> 6, lane = tid & 63;
    const float* src[4];
    #pragma unroll
    for (int i = 0; i < 4; ++i) {
        int m = m0 + 4 * w + i;
        int ms = m < c ? m : c - 1;
        src[i] = hidden + ((size_t)lists[g * BATCH + ms] * NGRP + g) * DMODEL + lane * 4;
    }
    int dep = 0, s = 0;
    for (int rep = 0; rep < 64; ++rep) {
        asm volatile("" : "+v"(dep));
        stage_body(src, A, w, lane, dep);
        __syncthreads();
        s += A[tid & 15][(tid * 131 + rep) & 2047];   // keep-alive
        __syncthreads();
    }
    asm volatile("" :: "v"(s));
}

// ---------------- PROBE: compute-only x64 (stage once) ----------------
__global__ __launch_bounds__(256, 2) void probe_comp(
    const float* __restrict__ hidden, const float* __restrict__ bias,
    const int* __restrict__ gsizes, const int* __restrict__ cnt,
    const int* __restrict__ lists, const int* __restrict__ map,
    const unsigned short* __restrict__ Wb2, float* __restrict__ out)
{
    int e = map[blockIdx.x];
    if (e < 0) return;
    int g = e >> 16, t = e & 0xFFFF;
    int c = cnt[g * CNT_STRIDE];
    int m0 = t * TM;
    __shared__ unsigned short A[TM][DMODEL];
    int tid = threadIdx.x, w = tid >> 6, lane = tid & 63;
    int lrow = lane & 15, kg = lane >> 4;
    const float* src[4];
    #pragma unroll
    for (int i = 0; i < 4; ++i) {
        int m = m0 + 4 * w + i;
        int ms = m < c ? m : c - 1;
        src[i] = hidden + ((size_t)lists[g * BATCH + ms] * NGRP + g) * DMODEL + lane * 4;
    }
    stage_body(src, A, w, lane, 0);
    __syncthreads();
    const unsigned short* bp =
        Wb2 + (size_t)g * NKK * MAXGS * 32 + (w * 16 + lrow) * 32 + kg * 8;
    int dep = 0;
    for (int rep = 0; rep < 64; ++rep) {
        asm volatile("" : "+v"(dep));
        compute_body(A, bp, bias, gsizes, lists, out, g, m0, c, w, lrow, kg, dep);
    }
}

extern "C" void kernel_launch(void* const* d_in, const int* in_sizes, int n_in,
                              void* d_out, int out_size, void* d_ws, size_t ws_size,
                              hipStream_t stream) {
    const float* hidden = (const float*)d_in[0];
    const int*   chosen = (const int*)d_in[1];
    const float* W      = (const float*)d_in[2];
    const float* bias   = (const float*)d_in[3];
    const int*   gs     = (const int*)d_in[4];
    float* out = (float*)d_out;

    char* ws = (char*)d_ws;
    int* cnt   = (int*)(ws + CNT_OFF);
    int* hist  = (int*)(ws + HIST_OFF);
    int* map   = (int*)(ws + MAP_OFF);
    int* lists = (int*)(ws + LISTS_OFF);
    unsigned short* Wb2 = (unsigned short*)(ws + W_OFF);

    init_hist_kernel<<<dim3(1024 + NBLK), dim3(256), 0, stream>>>(W, chosen, Wb2, hist);
    scatter_kernel<<<dim3(NBLK), dim3(256), 0, stream>>>(chosen, hist, lists, cnt, map);
    // PROBES (idempotent outputs; real gemm runs last)
    probe_full<<<dim3(MAXTILES), dim3(256), 0, stream>>>(
        hidden, bias, gs, cnt, lists, map, Wb2, out);
    probe_stage<<<dim3(MAXTILES), dim3(256), 0, stream>>>(hidden, cnt, lists, map);
    probe_comp<<<dim3(MAXTILES), dim3(256), 0, stream>>>(
        hidden, bias, gs, cnt, lists, map, Wb2, out);
    // REAL pipeline output
    gemm_kernel<<<dim3(MAXTILES), dim3(256), 0, stream>>>(
        hidden, bias, gs, cnt, lists, map, Wb2, out);
}

// Round 21
// 37.363 us; speedup vs baseline: 40.4948x; 40.4948x over previous
//
#include <hip/hip_runtime.h>
#include <hip/hip_bf16.h>

// Problem constants
#define BATCH   8192
#define NGRP    8
#define MAXGS   64
#define DMODEL  2048
#define TM      16
#define NBLK    32
#define NKK     (DMODEL / 32)     // 64 K-chunks of 32
#define KC      512               // f32 per chunk-row
#define NCH     (DMODEL / KC)     // 4 chunks
#define KKP     (KC / 32)         // 16 kk per chunk
#define MAXTILES 520

typedef __attribute__((ext_vector_type(8))) short  short8;
typedef __attribute__((ext_vector_type(4))) float  f32x4;

// ws layout
#define CNT_OFF   0
#define HIST_OFF  512
#define MAP_OFF   1536
#define LISTS_OFF 4096
#define W_OFF     (LISTS_OFF + NGRP * BATCH * 4)
#define CNT_STRIDE 16

static __device__ __forceinline__ short bf(float f) {
    __hip_bfloat16 h = __float2bfloat16(f);
    return (short)__bfloat16_as_ushort(h);
}

// Phase 0 (fused): W repack (Wall-B fix) + per-block group histograms.
__global__ __launch_bounds__(256) void init_hist_kernel(
    const float* __restrict__ W,
    const int* __restrict__ chosen,
    unsigned short* __restrict__ Wb2,
    int* __restrict__ hist)
{
    int blk = blockIdx.x;
    int tid = threadIdx.x;
    if (blk < 1024) {
        int e = (blk * 256 + tid) * 4;
        int g = e >> 17;
        int rem = e & ((MAXGS * DMODEL) - 1);
        int c = rem >> 11;
        int k = rem & (DMODEL - 1);
        int kk = k >> 5, j = k & 31;
        float4 w = *reinterpret_cast<const float4*>(W + e);
        ushort4 o;
        o.x = (unsigned short)bf(w.x); o.y = (unsigned short)bf(w.y);
        o.z = (unsigned short)bf(w.z); o.w = (unsigned short)bf(w.w);
        size_t dst = (((size_t)g * NKK + kk) * MAXGS + c) * 32 + j;
        *reinterpret_cast<ushort4*>(Wb2 + dst) = o;
    } else {
        int hb = blk - 1024;
        __shared__ int h[NGRP];
        if (tid < NGRP) h[tid] = 0;
        __syncthreads();
        int g = chosen[hb * 256 + tid];
        atomicAdd(&h[g], 1);
        __syncthreads();
        if (tid < NGRP) hist[hb * NGRP + tid] = h[tid];
    }
}

// Phase 1: scan fused into scatter + tile directory (r19, bug-fixed form).
__global__ __launch_bounds__(256) void scatter_kernel(const int* __restrict__ chosen,
                                                      const int* __restrict__ hist,
                                                      int* __restrict__ lists,
                                                      int* __restrict__ cnt,
                                                      int* __restrict__ map) {
    __shared__ int hloc[NBLK * NGRP];
    __shared__ int gbase[NGRP];
    __shared__ int ntl[NGRP];
    __shared__ int wcnt[4][NGRP];
    __shared__ int wbase[4][NGRP];
    int tid  = threadIdx.x;
    int blk  = blockIdx.x;
    int w    = tid >> 6;
    int lane = tid & 63;

    if (tid < NBLK * NGRP) hloc[tid] = hist[tid];
    __syncthreads();
    if (tid < NGRP) {
        int s = 0;
        for (int b2 = 0; b2 < blk; ++b2) s += hloc[b2 * NGRP + tid];
        gbase[tid] = s;
        int tot = s;
        for (int b2 = blk; b2 < NBLK; ++b2) tot += hloc[b2 * NGRP + tid];
        ntl[tid] = (tot + TM - 1) / TM;
        if (blk == 0) cnt[tid * CNT_STRIDE] = tot;
    }
    __syncthreads();

    if (blk == 0) {
        for (int q = tid; q < MAXTILES; q += 256) map[q] = -1;
        __syncthreads();
        for (int p = tid; p < NGRP * 512; p += 256) {
            int t = p >> 3, gg = p & 7;
            if (t < ntl[gg]) {
                int pos = 0;
                #pragma unroll
                for (int g2 = 0; g2 < NGRP; ++g2) {
                    int nt = ntl[g2];
                    pos += (t < nt ? t : nt);
                    pos += (g2 < gg && nt > t) ? 1 : 0;
                }
                map[pos] = (gg << 16) | t;
            }
        }
    }

    int b = blk * 256 + tid;
    int g = chosen[b];
    int rank = 0;
    unsigned long long below = (1ull << lane) - 1ull;
    #pragma unroll
    for (int gg = 0; gg < NGRP; ++gg) {
        unsigned long long m = __ballot(g == gg);
        if (g == gg) rank = __popcll(m & below);
        if (lane == gg) wcnt[w][gg] = __popcll(m);
    }
    __syncthreads();
    if (tid < NGRP) {
        int base = gbase[tid];
        #pragma unroll
        for (int ww = 0; ww < 4; ++ww) {
            wbase[ww][tid] = base;
            base += wcnt[ww][tid];
        }
    }
    __syncthreads();
    lists[g * BATCH + wbase[w][g] + rank] = b;
}

// Phase 2: K-chunked double-buffered gemm.
// r20 probes: stage 10.5us(cold) + compute 12.1us, SERIAL (monolithic phases
// -> chip-wide HBM burst then compute burst). Fixes:
//  (1) SWIZZLE BUG: old bit6 = (lrow&1)<<6 OR'd with (lrow&7)<<4's bit6 ->
//      slot bit6 = lrow2|lrow0 = 1 for 12/16 rows -> 12-way pileup on one
//      16B bank slot (6.75e7 conflict-cy measured). New: bit6 = lrow>>3 ->
//      exact 8 lanes/slot = the 128B/cy LDS floor.
//  (2) KC=512 double-buffer (2x16KB LDS = 32KB) -> 4 blocks/CU; blocks at
//      drifting chunk phases overlap HBM-stage with L2/MFMA-compute (m114
//      cross-wave overlap) -- the overlap monolithic phases forbade.
//      Within-wave stage->compute stays serial (in-order vmcnt, r7/r16).
__global__ __launch_bounds__(256, 4) void gemm_kernel(
    const float* __restrict__ hidden,
    const float* __restrict__ bias,
    const int* __restrict__ gsizes,
    const int* __restrict__ cnt,
    const int* __restrict__ lists,
    const int* __restrict__ map,
    const unsigned short* __restrict__ Wb2,
    float* __restrict__ out)
{
    int e = map[blockIdx.x];
    if (e < 0) return;             // sentinel (<=8)
    int g = e >> 16;
    int t = e & 0xFFFF;
    int c = cnt[g * CNT_STRIDE];
    int m0 = t * TM;

    __shared__ unsigned short A[2][TM][KC];   // bf16, 2 x 16 KB

    int tid  = threadIdx.x;
    int w    = tid >> 6;           // wave 0..3
    int lane = tid & 63;
    int lrow = lane & 15;
    int kg   = lane >> 4;          // 0..3

    // wave w stages rows 4w..4w+3; lane covers 8 consecutive f32 per row
    const float* src[4];
    #pragma unroll
    for (int i = 0; i < 4; ++i) {
        int m  = m0 + 4 * w + i;
        int ms = m < c ? m : c - 1;          // tail: dup last row (guarded)
        src[i] = hidden + ((size_t)lists[g * BATCH + ms] * NGRP + g) * DMODEL
               + lane * 8;
    }

    // ---- stage one chunk into buf: 2KB burst per row, cvt, swizzled write
    auto STAGE = [&](int buf, int ch) {
        f32x4 v0[4], v1[4];
        #pragma unroll
        for (int i = 0; i < 4; ++i) {
            v0[i] = *reinterpret_cast<const f32x4*>(src[i] + ch * KC);
            v1[i] = *reinterpret_cast<const f32x4*>(src[i] + ch * KC + 4);
        }
        #pragma unroll
        for (int i = 0; i < 4; ++i) {
            int r = 4 * w + i;
            int swz = ((r & 3) << 4) | (((r >> 3) & 1) << 6);
            short8 o;
            o[0] = bf(v0[i][0]); o[1] = bf(v0[i][1]);
            o[2] = bf(v0[i][2]); o[3] = bf(v0[i][3]);
            o[4] = bf(v1[i][0]); o[5] = bf(v1[i][1]);
            o[6] = bf(v1[i][2]); o[7] = bf(v1[i][3]);
            char* ab = (char*)&A[buf][r][0];
            *reinterpret_cast<short8*>(ab + ((lane * 16) ^ swz)) = o;
        }
    };

    int swzr = ((lrow & 3) << 4) | (((lrow >> 3) & 1) << 6);
    const unsigned short* bp =
        Wb2 + (size_t)g * NKK * MAXGS * 32 + (w * 16 + lrow) * 32 + kg * 8;
    f32x4 acc = f32x4{0, 0, 0, 0};

    STAGE(0, 0);
    __syncthreads();
    #pragma unroll
    for (int ch = 0; ch < NCH; ++ch) {
        if (ch + 1 < NCH) STAGE((ch + 1) & 1, ch + 1);   // writes other buffer
        const char* abase = (const char*)&A[ch & 1][lrow][0];
        #pragma unroll 8
        for (int k2 = 0; k2 < KKP; ++k2) {
            int byte = (k2 * 64 + kg * 16) ^ swzr;
            short8 af  = *reinterpret_cast<const short8*>(abase + byte);
            short8 bfr = *reinterpret_cast<const short8*>(
                bp + (size_t)(ch * KKP + k2) * MAXGS * 32);
            acc = __builtin_amdgcn_mfma_f32_16x16x32_bf16(af, bfr, acc, 0, 0, 0);
        }
        __syncthreads();   // stage(ch+1) visible; compute(ch) done before
                           // buf[ch&1] is overwritten next iteration
    }

    // epilogue: C col = lrow (n within group), row = kg*4 + r
    int gsz = gsizes[g];
    int n = w * 16 + lrow;
    float bv = bias[g * MAXGS + n];
    #pragma unroll
    for (int r = 0; r < 4; ++r) {
        int m = m0 + kg * 4 + r;
        if (m < c) {
            int s = lists[g * BATCH + m];
            out[(size_t)s * MAXGS + n] = acc[r] + bv;   // padded n: 0+0 == 0
            out[(size_t)(BATCH + s) * MAXGS + n] = (n < gsz) ? 1.0f : 0.0f;
        }
    }
}

extern "C" void kernel_launch(void* const* d_in, const int* in_sizes, int n_in,
                              void* d_out, int out_size, void* d_ws, size_t ws_size,
                              hipStream_t stream) {
    const float* hidden = (const float*)d_in[0];   // [8192, 8, 2048] f32
    const int*   chosen = (const int*)d_in[1];     // [8192] i32
    const float* W      = (const float*)d_in[2];   // [8, 64, 2048] f32 (zero-padded)
    const float* bias   = (const float*)d_in[3];   // [8, 64] f32 (zero-padded)
    const int*   gs     = (const int*)d_in[4];     // [8] i32
    float* out = (float*)d_out;                    // [8192*64 preds | 8192*64 valid]

    char* ws = (char*)d_ws;
    int* cnt   = (int*)(ws + CNT_OFF);
    int* hist  = (int*)(ws + HIST_OFF);
    int* map   = (int*)(ws + MAP_OFF);
    int* lists = (int*)(ws + LISTS_OFF);
    unsigned short* Wb2 = (unsigned short*)(ws + W_OFF);

    init_hist_kernel<<<dim3(1024 + NBLK), dim3(256), 0, stream>>>(W, chosen, Wb2, hist);
    scatter_kernel<<<dim3(NBLK), dim3(256), 0, stream>>>(chosen, hist, lists, cnt, map);
    gemm_kernel<<<dim3(MAXTILES), dim3(256), 0, stream>>>(
        hidden, bias, gs, cnt, lists, map, Wb2, out);
}